// Round 22
// baseline (223.978 us; speedup 1.0000x reference)
//
#include <hip/hip_runtime.h>

// Problem constants: B=4, S=2048, D=1024, H=16, depth=64
#define SB 4
#define SS 2048
#define SD 1024
#define SH 16

typedef float f32x4 __attribute__((ext_vector_type(4)));
typedef __bf16 bf16x8 __attribute__((ext_vector_type(8)));
typedef short short4v __attribute__((ext_vector_type(4)));
typedef unsigned int uint2v __attribute__((ext_vector_type(2)));

__device__ __forceinline__ unsigned short f2bf_(float x) {
    unsigned u = __builtin_bit_cast(unsigned, x);
    unsigned r = u + 0x7FFFu + ((u >> 16) & 1u);
    return (unsigned short)(r >> 16);
}

#define GL2LDS(g, l) __builtin_amdgcn_global_load_lds( \
    (const __attribute__((address_space(1))) unsigned int*)(g), \
    (__attribute__((address_space(3))) unsigned int*)(l), 16, 0, 0)

// ---------------------------------------------------------------------------
// Transpose+convert 4 weight matrices fp32[1024,1024] -> bf16 [1024,1024]^T
// PLUS (z==4 slice) mask -> additive log2-domain term MA = mask*MSK - 8.
// ---------------------------------------------------------------------------
__global__ __launch_bounds__(256) void transpose4(
        const float* __restrict__ w0, const float* __restrict__ w1,
        const float* __restrict__ w2, const float* __restrict__ w3,
        unsigned short* __restrict__ out,
        const int* __restrict__ mk, float* __restrict__ MA) {
    int zz = blockIdx.z;
    if (zz == 4) {
        if (blockIdx.y != 0) return;
        int i = blockIdx.x * 256 + threadIdx.y * 32 + threadIdx.x;
        if (i < SB * SS)
            MA[i] = (float)mk[i] * (-1e9f * 1.4426950408889634f) - 8.0f;
        return;
    }
    __shared__ unsigned short tile[32][33];
    const float* src = (zz == 0) ? w0 : (zz == 1) ? w1 : (zz == 2) ? w2 : w3;
    unsigned short* dst = out + (size_t)zz * 1024 * 1024;
    int x = blockIdx.x * 32 + threadIdx.x;
    int y0 = blockIdx.y * 32;
    for (int j = threadIdx.y; j < 32; j += 8)
        tile[j][threadIdx.x] = f2bf_(src[(size_t)(y0 + j) * 1024 + x]);
    __syncthreads();
    int ox = y0 + threadIdx.x;
    int oy0 = blockIdx.x * 32;
    for (int j = threadIdx.y; j < 32; j += 8)
        dst[(size_t)(oy0 + j) * 1024 + ox] = tile[threadIdx.x][j];
}

// ---------------------------------------------------------------------------
// Fused Q/K/V projection GEMM, BK=64 (halved barrier count vs round 20/21):
// zone-sequential grid (64, 8, 3), 8 waves per 128x128 tile.
// A: reg-staged fp32->bf16, 4x float4/thread/tile, 2x ds_write_b128 into
//    padded [128][136] rows (banks 2-way, free; pad legal, no gl2lds on A).
// B: [128][64] via 2x gl2lds/thread, XOR swizzle c8^(r&7) (attn-K-proven).
// COMPUTE: 2 k-subtiles = 16 MFMA per barrier (vs 8).
// ---------------------------------------------------------------------------
__global__ __launch_bounds__(512) void gemm_qkv(
        const float* __restrict__ Aq, const float* __restrict__ Ak,
        const float* __restrict__ Avv, const unsigned short* __restrict__ WT,
        const float* __restrict__ bq, const float* __restrict__ bk,
        const float* __restrict__ bv, unsigned short* __restrict__ Qh,
        unsigned short* __restrict__ Kh, unsigned short* __restrict__ VTr,
        float qscl) {
    const int K = 1024, N = 1024;
    __shared__ alignas(16) unsigned short Asm[2][128][136];  // BK=64 + 8 pad
    __shared__ alignas(16) unsigned short Bsm[2][128][64];
    const int zone = blockIdx.z;
    const float* Af = (zone == 0) ? Aq : (zone == 1) ? Ak : Avv;
    const unsigned short* BT = WT + (size_t)zone * 1048576;
    const float* bias = (zone == 0) ? bq : (zone == 1) ? bk : bv;

    const int m0 = blockIdx.x * 128, n0 = blockIdx.y * 128;
    const int tid = threadIdx.x;
    const int lane = tid & 63, wid = tid >> 6;
    const int wr = wid >> 2, wc = wid & 3;
    const int cl = lane & 15, kg = lane >> 4;
    const int arow = tid >> 2, aseg = tid & 3;   // A: 4 thr/row, 32B segs

    f32x4 acc[4][2] = {};
    f32x4 ra0[4], ra1[4];                        // two A tiles in flight

    auto LOADA = [&](int k0, f32x4* r) {
        const float* p = Af + (size_t)(m0 + arow) * K + k0 + aseg * 16;
        r[0] = *(const f32x4*)p;
        r[1] = *(const f32x4*)(p + 4);
        r[2] = *(const f32x4*)(p + 8);
        r[3] = *(const f32x4*)(p + 12);
    };
    auto WRITEA = [&](int buf, const f32x4* r) {
        bf16x8 w0v, w1v;
#pragma unroll
        for (int e = 0; e < 4; ++e) {
            w0v[e] = (__bf16)r[0][e];
            w0v[4 + e] = (__bf16)r[1][e];
            w1v[e] = (__bf16)r[2][e];
            w1v[4 + e] = (__bf16)r[3][e];
        }
        *(bf16x8*)&Asm[buf][arow][aseg * 16] = w0v;
        *(bf16x8*)&Asm[buf][arow][aseg * 16 + 8] = w1v;
    };
    auto STAGEB = [&](int buf, int k0) {
        // 128 rows x 8 chunks = 1024 chunks; 2 per thread
#pragma unroll
        for (int i = 0; i < 2; ++i) {
            int base = i * 64 + wid * 8;
            int row = base + (lane >> 3);
            int cs = (lane & 7) ^ (row & 7);
            GL2LDS(BT + (size_t)(n0 + row) * K + k0 + cs * 8, &Bsm[buf][base][0]);
        }
    };
    auto COMPUTE = [&](int buf) {
#pragma unroll
        for (int ksub = 0; ksub < 2; ++ksub) {
            bf16x8 af[4], bfv[2];
#pragma unroll
            for (int mi = 0; mi < 4; ++mi) {
                int r = wr * 64 + mi * 16 + cl;
                af[mi] = *(const bf16x8*)&Asm[buf][r][ksub * 32 + kg * 8];
            }
#pragma unroll
            for (int ni = 0; ni < 2; ++ni) {
                int r = wc * 32 + ni * 16 + cl;
                bfv[ni] = *(const bf16x8*)&Bsm[buf][r][(((ksub * 4 + kg) ^ (r & 7))) * 8];
            }
#pragma unroll
            for (int mi = 0; mi < 4; ++mi)
#pragma unroll
                for (int ni = 0; ni < 2; ++ni)
                    acc[mi][ni] = __builtin_amdgcn_mfma_f32_16x16x32_bf16(
                        af[mi], bfv[ni], acc[mi][ni], 0, 0, 0);
        }
    };

    // 16 tiles of K=64. Prologue: tile0 -> buf0; tile1 -> ra1.
    LOADA(0, ra0);
    STAGEB(0, 0);
    WRITEA(0, ra0);
    LOADA(64, ra1);
    __syncthreads();

#pragma unroll 1
    for (int tt = 0; tt < 8; ++tt) {
        int t0 = 2 * tt;                                  // tile index
        if (t0 + 2 < 16) LOADA(t0 * 64 + 128, ra0);       // tile t0+2
        STAGEB(1, t0 * 64 + 64);                          // tile t0+1 -> buf1
        COMPUTE(0);
        WRITEA(1, ra1);
        __syncthreads();
        if (t0 + 3 < 16) LOADA(t0 * 64 + 192, ra1);       // tile t0+3
        if (t0 + 2 < 16) STAGEB(0, t0 * 64 + 128);        // tile t0+2 -> buf0
        COMPUTE(1);
        if (t0 + 2 < 16) WRITEA(0, ra0);
        __syncthreads();
    }

    const int rl = (lane >> 4) * 4;
    float os = (zone == 0) ? qscl : 1.0f;
#pragma unroll
    for (int mi = 0; mi < 4; ++mi) {
#pragma unroll
        for (int ni = 0; ni < 2; ++ni) {
            int row = m0 + wr * 64 + mi * 16 + rl;
            int col = n0 + wc * 32 + ni * 16 + cl;
            float bvv = bias[col];
            f32x4 v = acc[mi][ni];
            if (zone < 2) {
                unsigned short* C = (zone == 0) ? Qh : Kh;
#pragma unroll
                for (int j = 0; j < 4; ++j)
                    C[(size_t)(row + j) * N + col] = f2bf_((v[j] + bvv) * os);
            } else {
                int bb = row >> 11, s = row & 2047;
                short4v pk;
#pragma unroll
                for (int j = 0; j < 4; ++j)
                    pk[j] = (short)f2bf_(v[j] + bvv);
                *(short4v*)&VTr[((size_t)(bb * 1024 + col)) * 2048 + s] = pk;
            }
        }
    }
}

// ---------------------------------------------------------------------------
// O-projection GEMM (byte-identical): C[M,N] fp32 = A bf16 @ BT^T + bias.
// ---------------------------------------------------------------------------
__global__ __launch_bounds__(256) void gemm_out(
        const unsigned short* __restrict__ Ab, const unsigned short* __restrict__ BT,
        const float* __restrict__ bias, float* __restrict__ C,
        int M, int N, int K) {
    __shared__ alignas(16) unsigned short Asmb[2][128][32];
    __shared__ alignas(16) unsigned short Bsm[2][128][32];
    const int m0 = blockIdx.x * 128, n0 = blockIdx.y * 128;
    const int lane = threadIdx.x & 63, wid = threadIdx.x >> 6;
    const int wr = wid >> 1, wc = wid & 1;
    const int cl = lane & 15, kg = lane >> 4;

    f32x4 acc[4][4] = {};

    auto STAGE = [&](int buf, int k0) {
#pragma unroll
        for (int i = 0; i < 2; ++i) {
            int base = (i * 4 + wid) * 16;
            int row = base + (lane >> 2);
            int cs = (lane & 3) ^ ((row >> 1) & 3);
            GL2LDS(Ab + (size_t)(m0 + row) * K + k0 + cs * 8, &Asmb[buf][base][0]);
            GL2LDS(BT + (size_t)(n0 + row) * K + k0 + cs * 8, &Bsm[buf][base][0]);
        }
    };

    STAGE(0, 0);
    __syncthreads();

    for (int k0 = 0; k0 < K; k0 += 32) {
        int cur = (k0 >> 5) & 1;
        if (k0 + 32 < K) STAGE(cur ^ 1, k0 + 32);

        bf16x8 af[4], bfv[4];
#pragma unroll
        for (int mi = 0; mi < 4; ++mi) {
            int r = wr * 64 + mi * 16 + cl;
            af[mi] = *(const bf16x8*)&Asmb[cur][r][(kg ^ ((r >> 1) & 3)) * 8];
        }
#pragma unroll
        for (int ni = 0; ni < 4; ++ni) {
            int r = wc * 64 + ni * 16 + cl;
            bfv[ni] = *(const bf16x8*)&Bsm[cur][r][(kg ^ ((r >> 1) & 3)) * 8];
        }
#pragma unroll
        for (int mi = 0; mi < 4; ++mi)
#pragma unroll
            for (int ni = 0; ni < 4; ++ni)
                acc[mi][ni] = __builtin_amdgcn_mfma_f32_16x16x32_bf16(
                    af[mi], bfv[ni], acc[mi][ni], 0, 0, 0);
        __syncthreads();
    }

    const int rl = (lane >> 4) * 4;
#pragma unroll
    for (int mi = 0; mi < 4; ++mi) {
#pragma unroll
        for (int ni = 0; ni < 4; ++ni) {
            int row = m0 + wr * 64 + mi * 16 + rl;
            int col = n0 + wc * 64 + ni * 16 + cl;
            float bv = bias[col];
            f32x4 v = acc[mi][ni];
#pragma unroll
            for (int j = 0; j < 4; ++j)
                C[(size_t)(row + j) * N + col] = v[j] + bv;
        }
    }
}

// ---------------------------------------------------------------------------
// Flash attention v6.1 (byte-identical to round 21): 8 waves x 32 q-rows,
// KBLK=128, swapped QK^T, mask-seeded fixed-max softmax, interleaved
// QK->PV, ones-MFMA row sums, shuffle-free epilogue.
// ---------------------------------------------------------------------------
__global__ __launch_bounds__(512, 4) void attn_kernel(
        const unsigned short* __restrict__ Qp, const unsigned short* __restrict__ Kp,
        const unsigned short* __restrict__ VT, const float* __restrict__ MA,
        unsigned short* __restrict__ O) {
    __shared__ alignas(16) unsigned short Klds[2][128][64];
    __shared__ alignas(16) unsigned short Vlds[2][64][128];
    const int lane = threadIdx.x & 63, wid = threadIdx.x >> 6;   // wid 0..7
    const int bh = blockIdx.x;
    const int b = bh >> 4, h = bh & 15;
    const int qt = blockIdx.y;
    const int qrow0 = qt * 256 + wid * 32;
    const int cl = lane & 15, kg = lane >> 4;

    bf16x8 qf[2][2];
#pragma unroll
    for (int qh = 0; qh < 2; ++qh)
#pragma unroll
        for (int kh = 0; kh < 2; ++kh)
            qf[qh][kh] = *(const bf16x8*)&Qp[(size_t)(b * SS + qrow0 + qh * 16 + cl) * SD
                                            + h * 64 + kh * 32 + kg * 8];

    const float* MAb = MA + b * SS;

    bf16x8 onesf;
#pragma unroll
    for (int e = 0; e < 8; ++e) onesf[e] = (__bf16)1.0f;

    f32x4 oacc[2][4] = {};
    f32x4 lacc[2] = {};

    auto STAGE = [&](int buf, int tt) {
        int kt = (tt & 15) * 128;
        {
            int r8 = lane >> 3, c8 = lane & 7;
#pragma unroll
            for (int i = 0; i < 2; ++i) {
                int r = i * 64 + wid * 8 + r8;
                int cs = c8 ^ (r & 7);
                GL2LDS(Kp + (size_t)(b * SS + kt + r) * SD + h * 64 + cs * 8,
                       &Klds[buf][i * 64 + wid * 8][0]);
            }
        }
        {
            int r16 = lane >> 4, c16 = lane & 15;
#pragma unroll
            for (int i = 0; i < 2; ++i) {
                int r = i * 32 + wid * 4 + r16;
                int cs = (c16 & 8) | ((c16 & 7) ^ (r & 7));
                GL2LDS(VT + (size_t)(b * 1024 + h * 64 + r) * 2048 + kt + cs * 8,
                       &Vlds[buf][i * 32 + wid * 4][0]);
            }
        }
    };

    auto QKCOL = [&](int buf, int kt, int cf, f32x4* sv) {
        int r = cf * 16 + cl;
        bf16x8 kf0 = *(const bf16x8*)&Klds[buf][r][((0 + kg) ^ (r & 7)) * 8];
        bf16x8 kf1 = *(const bf16x8*)&Klds[buf][r][((4 + kg) ^ (r & 7)) * 8];
        f32x4 M = *(const f32x4*)&MAb[kt + cf * 16 + 4 * kg];
        __builtin_amdgcn_s_setprio(1);
#pragma unroll
        for (int qh = 0; qh < 2; ++qh) {
            f32x4 s = M;                                   // mask-seeded C-in
            s = __builtin_amdgcn_mfma_f32_16x16x32_bf16(kf0, qf[qh][0], s, 0, 0, 0);
            s = __builtin_amdgcn_mfma_f32_16x16x32_bf16(kf1, qf[qh][1], s, 0, 0, 0);
#pragma unroll
            for (int j = 0; j < 4; ++j)
                s[j] = __builtin_amdgcn_exp2f(s[j]);
            sv[qh] = s;
        }
        __builtin_amdgcn_s_setprio(0);
    };

    auto STEP = [&](int buf, int t) {
        int kt = t * 128;
#pragma unroll
        for (int ks = 0; ks < 4; ++ks) {
            f32x4 sA[2], sB[2];
            QKCOL(buf, kt, ks, sA);
            QKCOL(buf, kt, ks + 4, sB);
            bf16x8 pa[2];
#pragma unroll
            for (int qh = 0; qh < 2; ++qh) {
                pa[qh][0] = (__bf16)sA[qh][0];
                pa[qh][1] = (__bf16)sA[qh][1];
                pa[qh][2] = (__bf16)sA[qh][2];
                pa[qh][3] = (__bf16)sA[qh][3];
                pa[qh][4] = (__bf16)sB[qh][0];
                pa[qh][5] = (__bf16)sB[qh][1];
                pa[qh][6] = (__bf16)sB[qh][2];
                pa[qh][7] = (__bf16)sB[qh][3];
            }
            __builtin_amdgcn_s_setprio(1);
#pragma unroll
            for (int qh = 0; qh < 2; ++qh)
                lacc[qh] = __builtin_amdgcn_mfma_f32_16x16x32_bf16(
                    pa[qh], onesf, lacc[qh], 0, 0, 0);
#pragma unroll
            for (int nf = 0; nf < 4; ++nf) {
                int d = nf * 16 + cl;
                int c16a = 2 * ks + (kg >> 1);
                int c16b = 2 * (ks + 4) + (kg >> 1);
                int cha = (c16a & 8) | ((c16a & 7) ^ (d & 7));
                int chb = (c16b & 8) | ((c16b & 7) ^ (d & 7));
                const char* vb = (const char*)&Vlds[buf][d][0];
                uint2v lo = *(const uint2v*)(vb + cha * 16 + (kg & 1) * 8);
                uint2v hi = *(const uint2v*)(vb + chb * 16 + (kg & 1) * 8);
                bf16x8 vf;
                *(uint2v*)&vf = lo;
                *((uint2v*)&vf + 1) = hi;
#pragma unroll
                for (int qh = 0; qh < 2; ++qh)
                    oacc[qh][nf] = __builtin_amdgcn_mfma_f32_16x16x32_bf16(
                        pa[qh], vf, oacc[qh][nf], 0, 0, 0);
            }
            __builtin_amdgcn_s_setprio(0);
        }
    };

    STAGE(0, 0);
    __syncthreads();
    for (int t = 0; t < 16; ++t) {
        int cur = t & 1;
        STAGE(cur ^ 1, t + 1);
        STEP(cur, t);
        __syncthreads();
    }

#pragma unroll
    for (int qh = 0; qh < 2; ++qh) {
#pragma unroll
        for (int j = 0; j < 4; ++j) {
            float inv = 1.0f / lacc[qh][j];
#pragma unroll
            for (int nf = 0; nf < 4; ++nf)
                O[(size_t)(b * SS + qrow0 + qh * 16 + 4 * kg + j) * SD + h * 64 + nf * 16 + cl] =
                    f2bf_(oacc[qh][nf][j] * inv);
        }
    }
}

// ---------------------------------------------------------------------------
extern "C" void kernel_launch(void* const* d_in, const int* in_sizes, int n_in,
                              void* d_out, int out_size, void* d_ws, size_t ws_size,
                              hipStream_t stream) {
    const float* q  = (const float*)d_in[0];
    const float* k  = (const float*)d_in[1];
    const float* v  = (const float*)d_in[2];
    const int*   mk = (const int*)d_in[3];
    const float* wq = (const float*)d_in[4];
    const float* bq = (const float*)d_in[5];
    const float* wk = (const float*)d_in[6];
    const float* bk = (const float*)d_in[7];
    const float* wv = (const float*)d_in[8];
    const float* bv = (const float*)d_in[9];
    const float* wo = (const float*)d_in[10];
    const float* bo = (const float*)d_in[11];
    float* out = (float*)d_out;

    char* ws = (char*)d_ws;
    unsigned short* WT  = (unsigned short*)ws;                   // 8 MB
    unsigned short* X   = (unsigned short*)(ws + 8388608);       // attn out (bf16)
    unsigned short* Qh  = (unsigned short*)(ws + 25165824);
    unsigned short* Kh  = (unsigned short*)(ws + 41943040);
    unsigned short* VTr = (unsigned short*)(ws + 58720256);
    float*          MAf = (float*)(ws + 75497472);               // 32 KB

    const float QSCL = 0.125f * 1.4426950408889634f;  // 1/sqrt(64) * log2(e)

    transpose4<<<dim3(32, 32, 5), dim3(32, 8), 0, stream>>>(
        wq, wk, wv, wo, WT, mk, MAf);

    gemm_qkv<<<dim3(64, 8, 3), dim3(512), 0, stream>>>(
        q, k, v, WT, bq, bk, bv, Qh, Kh, VTr, QSCL);

    attn_kernel<<<dim3(64, 8), dim3(512), 0, stream>>>(Qh, Kh, VTr, MAf, X);

    gemm_out<<<dim3(64, 8), dim3(256), 0, stream>>>(
        X, WT + 3 * 1048576, bo, out, 8192, 1024, 1024);
}

// Round 23
// 187.910 us; speedup vs baseline: 1.1919x; 1.1919x over previous
//
#include <hip/hip_runtime.h>

// Problem constants: B=4, S=2048, D=1024, H=16, depth=64
#define SB 4
#define SS 2048
#define SD 1024
#define SH 16

typedef float f32x4 __attribute__((ext_vector_type(4)));
typedef __bf16 bf16x8 __attribute__((ext_vector_type(8)));
typedef short short4v __attribute__((ext_vector_type(4)));
typedef unsigned int uint2v __attribute__((ext_vector_type(2)));

__device__ __forceinline__ unsigned short f2bf_(float x) {
    unsigned u = __builtin_bit_cast(unsigned, x);
    unsigned r = u + 0x7FFFu + ((u >> 16) & 1u);
    return (unsigned short)(r >> 16);
}

#define GL2LDS(g, l) __builtin_amdgcn_global_load_lds( \
    (const __attribute__((address_space(1))) unsigned int*)(g), \
    (__attribute__((address_space(3))) unsigned int*)(l), 16, 0, 0)

// ---------------------------------------------------------------------------
// Transpose+convert 4 weight matrices fp32[1024,1024] -> bf16 [1024,1024]^T
// PLUS (z==4 slice) mask -> additive log2-domain term MA = mask*MSK - 8.
// ---------------------------------------------------------------------------
__global__ __launch_bounds__(256) void transpose4(
        const float* __restrict__ w0, const float* __restrict__ w1,
        const float* __restrict__ w2, const float* __restrict__ w3,
        unsigned short* __restrict__ out,
        const int* __restrict__ mk, float* __restrict__ MA) {
    int zz = blockIdx.z;
    if (zz == 4) {
        if (blockIdx.y != 0) return;
        int i = blockIdx.x * 256 + threadIdx.y * 32 + threadIdx.x;
        if (i < SB * SS)
            MA[i] = (float)mk[i] * (-1e9f * 1.4426950408889634f) - 8.0f;
        return;
    }
    __shared__ unsigned short tile[32][33];
    const float* src = (zz == 0) ? w0 : (zz == 1) ? w1 : (zz == 2) ? w2 : w3;
    unsigned short* dst = out + (size_t)zz * 1024 * 1024;
    int x = blockIdx.x * 32 + threadIdx.x;
    int y0 = blockIdx.y * 32;
    for (int j = threadIdx.y; j < 32; j += 8)
        tile[j][threadIdx.x] = f2bf_(src[(size_t)(y0 + j) * 1024 + x]);
    __syncthreads();
    int ox = y0 + threadIdx.x;
    int oy0 = blockIdx.x * 32;
    for (int j = threadIdx.y; j < 32; j += 8)
        dst[(size_t)(oy0 + j) * 1024 + ox] = tile[threadIdx.x][j];
}

// ---------------------------------------------------------------------------
// Fused Q/K/V projection GEMM, BK=64, CORRECT LDS SIZING ([128][72] A tile;
// round 22's [128][136] was a sizing bug -> 100 KB -> 1 block/CU).
// LDS = 36864 + 32768 = 69632 B -> 2 blocks/CU, 16 waves/CU.
// Zone-sequential grid (64, 8, 3), 8 waves per 128x128 tile, 16 MFMA/barrier.
// A: reg-staged fp32->bf16, 4x float4/thread/tile, 2x ds_write_b128.
// B: [128][64] via 2x gl2lds/thread, XOR swizzle c8^(r&7).
// ---------------------------------------------------------------------------
__global__ __launch_bounds__(512) void gemm_qkv(
        const float* __restrict__ Aq, const float* __restrict__ Ak,
        const float* __restrict__ Avv, const unsigned short* __restrict__ WT,
        const float* __restrict__ bq, const float* __restrict__ bk,
        const float* __restrict__ bv, unsigned short* __restrict__ Qh,
        unsigned short* __restrict__ Kh, unsigned short* __restrict__ VTr,
        float qscl) {
    const int K = 1024, N = 1024;
    __shared__ alignas(16) unsigned short Asm[2][128][72];   // BK=64 + 8 pad
    __shared__ alignas(16) unsigned short Bsm[2][128][64];
    const int zone = blockIdx.z;
    const float* Af = (zone == 0) ? Aq : (zone == 1) ? Ak : Avv;
    const unsigned short* BT = WT + (size_t)zone * 1048576;
    const float* bias = (zone == 0) ? bq : (zone == 1) ? bk : bv;

    const int m0 = blockIdx.x * 128, n0 = blockIdx.y * 128;
    const int tid = threadIdx.x;
    const int lane = tid & 63, wid = tid >> 6;
    const int wr = wid >> 2, wc = wid & 3;
    const int cl = lane & 15, kg = lane >> 4;
    const int arow = tid >> 2, aseg = tid & 3;   // A: 4 thr/row, 32B segs

    f32x4 acc[4][2] = {};
    f32x4 ra0[4], ra1[4];                        // two A tiles in flight

    auto LOADA = [&](int k0, f32x4* r) {
        const float* p = Af + (size_t)(m0 + arow) * K + k0 + aseg * 16;
        r[0] = *(const f32x4*)p;
        r[1] = *(const f32x4*)(p + 4);
        r[2] = *(const f32x4*)(p + 8);
        r[3] = *(const f32x4*)(p + 12);
    };
    auto WRITEA = [&](int buf, const f32x4* r) {
        bf16x8 w0v, w1v;
#pragma unroll
        for (int e = 0; e < 4; ++e) {
            w0v[e] = (__bf16)r[0][e];
            w0v[4 + e] = (__bf16)r[1][e];
            w1v[e] = (__bf16)r[2][e];
            w1v[4 + e] = (__bf16)r[3][e];
        }
        *(bf16x8*)&Asm[buf][arow][aseg * 16] = w0v;
        *(bf16x8*)&Asm[buf][arow][aseg * 16 + 8] = w1v;
    };
    auto STAGEB = [&](int buf, int k0) {
#pragma unroll
        for (int i = 0; i < 2; ++i) {
            int base = i * 64 + wid * 8;
            int row = base + (lane >> 3);
            int cs = (lane & 7) ^ (row & 7);
            GL2LDS(BT + (size_t)(n0 + row) * K + k0 + cs * 8, &Bsm[buf][base][0]);
        }
    };
    auto COMPUTE = [&](int buf) {
#pragma unroll
        for (int ksub = 0; ksub < 2; ++ksub) {
            bf16x8 af[4], bfv[2];
#pragma unroll
            for (int mi = 0; mi < 4; ++mi) {
                int r = wr * 64 + mi * 16 + cl;
                af[mi] = *(const bf16x8*)&Asm[buf][r][ksub * 32 + kg * 8];
            }
#pragma unroll
            for (int ni = 0; ni < 2; ++ni) {
                int r = wc * 32 + ni * 16 + cl;
                bfv[ni] = *(const bf16x8*)&Bsm[buf][r][(((ksub * 4 + kg) ^ (r & 7))) * 8];
            }
#pragma unroll
            for (int mi = 0; mi < 4; ++mi)
#pragma unroll
                for (int ni = 0; ni < 2; ++ni)
                    acc[mi][ni] = __builtin_amdgcn_mfma_f32_16x16x32_bf16(
                        af[mi], bfv[ni], acc[mi][ni], 0, 0, 0);
        }
    };

    // 16 tiles of K=64. Prologue: tile0 -> buf0; tile1 -> ra1.
    LOADA(0, ra0);
    STAGEB(0, 0);
    WRITEA(0, ra0);
    LOADA(64, ra1);
    __syncthreads();

#pragma unroll 1
    for (int tt = 0; tt < 8; ++tt) {
        int t0 = 2 * tt;
        if (t0 + 2 < 16) LOADA(t0 * 64 + 128, ra0);
        STAGEB(1, t0 * 64 + 64);
        COMPUTE(0);
        WRITEA(1, ra1);
        __syncthreads();
        if (t0 + 3 < 16) LOADA(t0 * 64 + 192, ra1);
        if (t0 + 2 < 16) STAGEB(0, t0 * 64 + 128);
        COMPUTE(1);
        if (t0 + 2 < 16) WRITEA(0, ra0);
        __syncthreads();
    }

    const int rl = (lane >> 4) * 4;
    float os = (zone == 0) ? qscl : 1.0f;
#pragma unroll
    for (int mi = 0; mi < 4; ++mi) {
#pragma unroll
        for (int ni = 0; ni < 2; ++ni) {
            int row = m0 + wr * 64 + mi * 16 + rl;
            int col = n0 + wc * 32 + ni * 16 + cl;
            float bvv = bias[col];
            f32x4 v = acc[mi][ni];
            if (zone < 2) {
                unsigned short* C = (zone == 0) ? Qh : Kh;
#pragma unroll
                for (int j = 0; j < 4; ++j)
                    C[(size_t)(row + j) * N + col] = f2bf_((v[j] + bvv) * os);
            } else {
                int bb = row >> 11, s = row & 2047;
                short4v pk;
#pragma unroll
                for (int j = 0; j < 4; ++j)
                    pk[j] = (short)f2bf_(v[j] + bvv);
                *(short4v*)&VTr[((size_t)(bb * 1024 + col)) * 2048 + s] = pk;
            }
        }
    }
}

// ---------------------------------------------------------------------------
// O-projection GEMM (byte-identical): C[M,N] fp32 = A bf16 @ BT^T + bias.
// ---------------------------------------------------------------------------
__global__ __launch_bounds__(256) void gemm_out(
        const unsigned short* __restrict__ Ab, const unsigned short* __restrict__ BT,
        const float* __restrict__ bias, float* __restrict__ C,
        int M, int N, int K) {
    __shared__ alignas(16) unsigned short Asmb[2][128][32];
    __shared__ alignas(16) unsigned short Bsm[2][128][32];
    const int m0 = blockIdx.x * 128, n0 = blockIdx.y * 128;
    const int lane = threadIdx.x & 63, wid = threadIdx.x >> 6;
    const int wr = wid >> 1, wc = wid & 1;
    const int cl = lane & 15, kg = lane >> 4;

    f32x4 acc[4][4] = {};

    auto STAGE = [&](int buf, int k0) {
#pragma unroll
        for (int i = 0; i < 2; ++i) {
            int base = (i * 4 + wid) * 16;
            int row = base + (lane >> 2);
            int cs = (lane & 3) ^ ((row >> 1) & 3);
            GL2LDS(Ab + (size_t)(m0 + row) * K + k0 + cs * 8, &Asmb[buf][base][0]);
            GL2LDS(BT + (size_t)(n0 + row) * K + k0 + cs * 8, &Bsm[buf][base][0]);
        }
    };

    STAGE(0, 0);
    __syncthreads();

    for (int k0 = 0; k0 < K; k0 += 32) {
        int cur = (k0 >> 5) & 1;
        if (k0 + 32 < K) STAGE(cur ^ 1, k0 + 32);

        bf16x8 af[4], bfv[4];
#pragma unroll
        for (int mi = 0; mi < 4; ++mi) {
            int r = wr * 64 + mi * 16 + cl;
            af[mi] = *(const bf16x8*)&Asmb[cur][r][(kg ^ ((r >> 1) & 3)) * 8];
        }
#pragma unroll
        for (int ni = 0; ni < 4; ++ni) {
            int r = wc * 64 + ni * 16 + cl;
            bfv[ni] = *(const bf16x8*)&Bsm[cur][r][(kg ^ ((r >> 1) & 3)) * 8];
        }
#pragma unroll
        for (int mi = 0; mi < 4; ++mi)
#pragma unroll
            for (int ni = 0; ni < 4; ++ni)
                acc[mi][ni] = __builtin_amdgcn_mfma_f32_16x16x32_bf16(
                    af[mi], bfv[ni], acc[mi][ni], 0, 0, 0);
        __syncthreads();
    }

    const int rl = (lane >> 4) * 4;
#pragma unroll
    for (int mi = 0; mi < 4; ++mi) {
#pragma unroll
        for (int ni = 0; ni < 4; ++ni) {
            int row = m0 + wr * 64 + mi * 16 + rl;
            int col = n0 + wc * 64 + ni * 16 + cl;
            float bv = bias[col];
            f32x4 v = acc[mi][ni];
#pragma unroll
            for (int j = 0; j < 4; ++j)
                C[(size_t)(row + j) * N + col] = v[j] + bv;
        }
    }
}

// ---------------------------------------------------------------------------
// Flash attention v6.1 (byte-identical to rounds 21/22): 8 waves x 32 q-rows,
// KBLK=128, swapped QK^T, mask-seeded fixed-max softmax, interleaved
// QK->PV, ones-MFMA row sums, shuffle-free epilogue.
// ---------------------------------------------------------------------------
__global__ __launch_bounds__(512, 4) void attn_kernel(
        const unsigned short* __restrict__ Qp, const unsigned short* __restrict__ Kp,
        const unsigned short* __restrict__ VT, const float* __restrict__ MA,
        unsigned short* __restrict__ O) {
    __shared__ alignas(16) unsigned short Klds[2][128][64];
    __shared__ alignas(16) unsigned short Vlds[2][64][128];
    const int lane = threadIdx.x & 63, wid = threadIdx.x >> 6;   // wid 0..7
    const int bh = blockIdx.x;
    const int b = bh >> 4, h = bh & 15;
    const int qt = blockIdx.y;
    const int qrow0 = qt * 256 + wid * 32;
    const int cl = lane & 15, kg = lane >> 4;

    bf16x8 qf[2][2];
#pragma unroll
    for (int qh = 0; qh < 2; ++qh)
#pragma unroll
        for (int kh = 0; kh < 2; ++kh)
            qf[qh][kh] = *(const bf16x8*)&Qp[(size_t)(b * SS + qrow0 + qh * 16 + cl) * SD
                                            + h * 64 + kh * 32 + kg * 8];

    const float* MAb = MA + b * SS;

    bf16x8 onesf;
#pragma unroll
    for (int e = 0; e < 8; ++e) onesf[e] = (__bf16)1.0f;

    f32x4 oacc[2][4] = {};
    f32x4 lacc[2] = {};

    auto STAGE = [&](int buf, int tt) {
        int kt = (tt & 15) * 128;
        {
            int r8 = lane >> 3, c8 = lane & 7;
#pragma unroll
            for (int i = 0; i < 2; ++i) {
                int r = i * 64 + wid * 8 + r8;
                int cs = c8 ^ (r & 7);
                GL2LDS(Kp + (size_t)(b * SS + kt + r) * SD + h * 64 + cs * 8,
                       &Klds[buf][i * 64 + wid * 8][0]);
            }
        }
        {
            int r16 = lane >> 4, c16 = lane & 15;
#pragma unroll
            for (int i = 0; i < 2; ++i) {
                int r = i * 32 + wid * 4 + r16;
                int cs = (c16 & 8) | ((c16 & 7) ^ (r & 7));
                GL2LDS(VT + (size_t)(b * 1024 + h * 64 + r) * 2048 + kt + cs * 8,
                       &Vlds[buf][i * 32 + wid * 4][0]);
            }
        }
    };

    auto QKCOL = [&](int buf, int kt, int cf, f32x4* sv) {
        int r = cf * 16 + cl;
        bf16x8 kf0 = *(const bf16x8*)&Klds[buf][r][((0 + kg) ^ (r & 7)) * 8];
        bf16x8 kf1 = *(const bf16x8*)&Klds[buf][r][((4 + kg) ^ (r & 7)) * 8];
        f32x4 M = *(const f32x4*)&MAb[kt + cf * 16 + 4 * kg];
        __builtin_amdgcn_s_setprio(1);
#pragma unroll
        for (int qh = 0; qh < 2; ++qh) {
            f32x4 s = M;                                   // mask-seeded C-in
            s = __builtin_amdgcn_mfma_f32_16x16x32_bf16(kf0, qf[qh][0], s, 0, 0, 0);
            s = __builtin_amdgcn_mfma_f32_16x16x32_bf16(kf1, qf[qh][1], s, 0, 0, 0);
#pragma unroll
            for (int j = 0; j < 4; ++j)
                s[j] = __builtin_amdgcn_exp2f(s[j]);
            sv[qh] = s;
        }
        __builtin_amdgcn_s_setprio(0);
    };

    auto STEP = [&](int buf, int t) {
        int kt = t * 128;
#pragma unroll
        for (int ks = 0; ks < 4; ++ks) {
            f32x4 sA[2], sB[2];
            QKCOL(buf, kt, ks, sA);
            QKCOL(buf, kt, ks + 4, sB);
            bf16x8 pa[2];
#pragma unroll
            for (int qh = 0; qh < 2; ++qh) {
                pa[qh][0] = (__bf16)sA[qh][0];
                pa[qh][1] = (__bf16)sA[qh][1];
                pa[qh][2] = (__bf16)sA[qh][2];
                pa[qh][3] = (__bf16)sA[qh][3];
                pa[qh][4] = (__bf16)sB[qh][0];
                pa[qh][5] = (__bf16)sB[qh][1];
                pa[qh][6] = (__bf16)sB[qh][2];
                pa[qh][7] = (__bf16)sB[qh][3];
            }
            __builtin_amdgcn_s_setprio(1);
#pragma unroll
            for (int qh = 0; qh < 2; ++qh)
                lacc[qh] = __builtin_amdgcn_mfma_f32_16x16x32_bf16(
                    pa[qh], onesf, lacc[qh], 0, 0, 0);
#pragma unroll
            for (int nf = 0; nf < 4; ++nf) {
                int d = nf * 16 + cl;
                int c16a = 2 * ks + (kg >> 1);
                int c16b = 2 * (ks + 4) + (kg >> 1);
                int cha = (c16a & 8) | ((c16a & 7) ^ (d & 7));
                int chb = (c16b & 8) | ((c16b & 7) ^ (d & 7));
                const char* vb = (const char*)&Vlds[buf][d][0];
                uint2v lo = *(const uint2v*)(vb + cha * 16 + (kg & 1) * 8);
                uint2v hi = *(const uint2v*)(vb + chb * 16 + (kg & 1) * 8);
                bf16x8 vf;
                *(uint2v*)&vf = lo;
                *((uint2v*)&vf + 1) = hi;
#pragma unroll
                for (int qh = 0; qh < 2; ++qh)
                    oacc[qh][nf] = __builtin_amdgcn_mfma_f32_16x16x32_bf16(
                        pa[qh], vf, oacc[qh][nf], 0, 0, 0);
            }
            __builtin_amdgcn_s_setprio(0);
        }
    };

    STAGE(0, 0);
    __syncthreads();
    for (int t = 0; t < 16; ++t) {
        int cur = t & 1;
        STAGE(cur ^ 1, t + 1);
        STEP(cur, t);
        __syncthreads();
    }

#pragma unroll
    for (int qh = 0; qh < 2; ++qh) {
#pragma unroll
        for (int j = 0; j < 4; ++j) {
            float inv = 1.0f / lacc[qh][j];
#pragma unroll
            for (int nf = 0; nf < 4; ++nf)
                O[(size_t)(b * SS + qrow0 + qh * 16 + 4 * kg + j) * SD + h * 64 + nf * 16 + cl] =
                    f2bf_(oacc[qh][nf][j] * inv);
        }
    }
}

// ---------------------------------------------------------------------------
extern "C" void kernel_launch(void* const* d_in, const int* in_sizes, int n_in,
                              void* d_out, int out_size, void* d_ws, size_t ws_size,
                              hipStream_t stream) {
    const float* q  = (const float*)d_in[0];
    const float* k  = (const float*)d_in[1];
    const float* v  = (const float*)d_in[2];
    const int*   mk = (const int*)d_in[3];
    const float* wq = (const float*)d_in[4];
    const float* bq = (const float*)d_in[5];
    const float* wk = (const float*)d_in[6];
    const float* bk = (const float*)d_in[7];
    const float* wv = (const float*)d_in[8];
    const float* bv = (const float*)d_in[9];
    const float* wo = (const float*)d_in[10];
    const float* bo = (const float*)d_in[11];
    float* out = (float*)d_out;

    char* ws = (char*)d_ws;
    unsigned short* WT  = (unsigned short*)ws;                   // 8 MB
    unsigned short* X   = (unsigned short*)(ws + 8388608);       // attn out (bf16)
    unsigned short* Qh  = (unsigned short*)(ws + 25165824);
    unsigned short* Kh  = (unsigned short*)(ws + 41943040);
    unsigned short* VTr = (unsigned short*)(ws + 58720256);
    float*          MAf = (float*)(ws + 75497472);               // 32 KB

    const float QSCL = 0.125f * 1.4426950408889634f;  // 1/sqrt(64) * log2(e)

    transpose4<<<dim3(32, 32, 5), dim3(32, 8), 0, stream>>>(
        wq, wk, wv, wo, WT, mk, MAf);

    gemm_qkv<<<dim3(64, 8, 3), dim3(512), 0, stream>>>(
        q, k, v, WT, bq, bk, bv, Qh, Kh, VTr, QSCL);

    attn_kernel<<<dim3(64, 8), dim3(512), 0, stream>>>(Qh, Kh, VTr, MAf, X);

    gemm_out<<<dim3(64, 8), dim3(256), 0, stream>>>(
        X, WT + 3 * 1048576, bo, out, 8192, 1024, 1024);
}

// Round 24
// 179.362 us; speedup vs baseline: 1.2487x; 1.0477x over previous
//
#include <hip/hip_runtime.h>

// Problem constants: B=4, S=2048, D=1024, H=16, depth=64
#define SB 4
#define SS 2048
#define SD 1024
#define SH 16

typedef float f32x4 __attribute__((ext_vector_type(4)));
typedef __bf16 bf16x8 __attribute__((ext_vector_type(8)));
typedef short short4v __attribute__((ext_vector_type(4)));
typedef unsigned int uint2v __attribute__((ext_vector_type(2)));

__device__ __forceinline__ unsigned short f2bf_(float x) {
    unsigned u = __builtin_bit_cast(unsigned, x);
    unsigned r = u + 0x7FFFu + ((u >> 16) & 1u);
    return (unsigned short)(r >> 16);
}

#define GL2LDS(g, l) __builtin_amdgcn_global_load_lds( \
    (const __attribute__((address_space(1))) unsigned int*)(g), \
    (__attribute__((address_space(3))) unsigned int*)(l), 16, 0, 0)

// ---------------------------------------------------------------------------
// Transpose+convert 4 weight matrices fp32[1024,1024] -> bf16 [1024,1024]^T
// PLUS (z==4 slice) mask -> additive log2-domain term MA = mask*MSK - 8.
// ---------------------------------------------------------------------------
__global__ __launch_bounds__(256) void transpose4(
        const float* __restrict__ w0, const float* __restrict__ w1,
        const float* __restrict__ w2, const float* __restrict__ w3,
        unsigned short* __restrict__ out,
        const int* __restrict__ mk, float* __restrict__ MA) {
    int zz = blockIdx.z;
    if (zz == 4) {
        if (blockIdx.y != 0) return;
        int i = blockIdx.x * 256 + threadIdx.y * 32 + threadIdx.x;
        if (i < SB * SS)
            MA[i] = (float)mk[i] * (-1e9f * 1.4426950408889634f) - 8.0f;
        return;
    }
    __shared__ unsigned short tile[32][33];
    const float* src = (zz == 0) ? w0 : (zz == 1) ? w1 : (zz == 2) ? w2 : w3;
    unsigned short* dst = out + (size_t)zz * 1024 * 1024;
    int x = blockIdx.x * 32 + threadIdx.x;
    int y0 = blockIdx.y * 32;
    for (int j = threadIdx.y; j < 32; j += 8)
        tile[j][threadIdx.x] = f2bf_(src[(size_t)(y0 + j) * 1024 + x]);
    __syncthreads();
    int ox = y0 + threadIdx.x;
    int oy0 = blockIdx.x * 32;
    for (int j = threadIdx.y; j < 32; j += 8)
        dst[(size_t)(oy0 + j) * 1024 + ox] = tile[threadIdx.x][j];
}

// ---------------------------------------------------------------------------
// Fused Q/K/V projection GEMM (byte-identical to round 21, measured best):
// BK=32, zone-sequential grid (64, 8, 3), 8 waves per 128x128 tile,
// reg-staged bf16 A into padded [128][40] LDS, B via gl2lds+swizzle.
// ---------------------------------------------------------------------------
__global__ __launch_bounds__(512) void gemm_qkv(
        const float* __restrict__ Aq, const float* __restrict__ Ak,
        const float* __restrict__ Avv, const unsigned short* __restrict__ WT,
        const float* __restrict__ bq, const float* __restrict__ bk,
        const float* __restrict__ bv, unsigned short* __restrict__ Qh,
        unsigned short* __restrict__ Kh, unsigned short* __restrict__ VTr,
        float qscl) {
    const int K = 1024, N = 1024;
    __shared__ alignas(16) unsigned short Asm[2][128][40];
    __shared__ alignas(16) unsigned short Bsm[2][128][32];
    const int zone = blockIdx.z;
    const float* Af = (zone == 0) ? Aq : (zone == 1) ? Ak : Avv;
    const unsigned short* BT = WT + (size_t)zone * 1048576;
    const float* bias = (zone == 0) ? bq : (zone == 1) ? bk : bv;

    const int m0 = blockIdx.x * 128, n0 = blockIdx.y * 128;
    const int tid = threadIdx.x;
    const int lane = tid & 63, wid = tid >> 6;
    const int wr = wid >> 2, wc = wid & 3;
    const int cl = lane & 15, kg = lane >> 4;
    const int arow = tid >> 2, aseg = tid & 3;

    f32x4 acc[4][2] = {};
    f32x4 ra0[2], ra1[2];

    auto LOADA = [&](int k0, f32x4* r) {
        const float* p = Af + (size_t)(m0 + arow) * K + k0 + aseg * 8;
        r[0] = *(const f32x4*)p;
        r[1] = *(const f32x4*)(p + 4);
    };
    auto WRITEA = [&](int buf, const f32x4* r) {
        bf16x8 w;
#pragma unroll
        for (int e = 0; e < 4; ++e) {
            w[e] = (__bf16)r[0][e];
            w[4 + e] = (__bf16)r[1][e];
        }
        *(bf16x8*)&Asm[buf][arow][aseg * 8] = w;
    };
    auto STAGEB = [&](int buf, int k0) {
        int base = wid * 16;
        int row = base + (lane >> 2);
        int cs = (lane & 3) ^ ((row >> 1) & 3);
        GL2LDS(BT + (size_t)(n0 + row) * K + k0 + cs * 8, &Bsm[buf][base][0]);
    };
    auto COMPUTE = [&](int buf) {
        bf16x8 af[4], bfv[2];
#pragma unroll
        for (int mi = 0; mi < 4; ++mi) {
            int r = wr * 64 + mi * 16 + cl;
            af[mi] = *(const bf16x8*)&Asm[buf][r][kg * 8];
        }
#pragma unroll
        for (int ni = 0; ni < 2; ++ni) {
            int r = wc * 32 + ni * 16 + cl;
            bfv[ni] = *(const bf16x8*)&Bsm[buf][r][(kg ^ ((r >> 1) & 3)) * 8];
        }
#pragma unroll
        for (int mi = 0; mi < 4; ++mi)
#pragma unroll
            for (int ni = 0; ni < 2; ++ni)
                acc[mi][ni] = __builtin_amdgcn_mfma_f32_16x16x32_bf16(
                    af[mi], bfv[ni], acc[mi][ni], 0, 0, 0);
    };

    LOADA(0, ra0);
    STAGEB(0, 0);
    WRITEA(0, ra0);
    LOADA(32, ra1);
    __syncthreads();

#pragma unroll 1
    for (int tt = 0; tt < 16; ++tt) {
        int t0 = 2 * tt;
        if (t0 + 2 < 32) LOADA(t0 * 32 + 64, ra0);
        STAGEB(1, t0 * 32 + 32);
        COMPUTE(0);
        WRITEA(1, ra1);
        __syncthreads();
        if (t0 + 3 < 32) LOADA(t0 * 32 + 96, ra1);
        if (t0 + 2 < 32) STAGEB(0, t0 * 32 + 64);
        COMPUTE(1);
        if (t0 + 2 < 32) WRITEA(0, ra0);
        __syncthreads();
    }

    const int rl = (lane >> 4) * 4;
    float os = (zone == 0) ? qscl : 1.0f;
#pragma unroll
    for (int mi = 0; mi < 4; ++mi) {
#pragma unroll
        for (int ni = 0; ni < 2; ++ni) {
            int row = m0 + wr * 64 + mi * 16 + rl;
            int col = n0 + wc * 32 + ni * 16 + cl;
            float bvv = bias[col];
            f32x4 v = acc[mi][ni];
            if (zone < 2) {
                unsigned short* C = (zone == 0) ? Qh : Kh;
#pragma unroll
                for (int j = 0; j < 4; ++j)
                    C[(size_t)(row + j) * N + col] = f2bf_((v[j] + bvv) * os);
            } else {
                int bb = row >> 11, s = row & 2047;
                short4v pk;
#pragma unroll
                for (int j = 0; j < 4; ++j)
                    pk[j] = (short)f2bf_(v[j] + bvv);
                *(short4v*)&VTr[((size_t)(bb * 1024 + col)) * 2048 + s] = pk;
            }
        }
    }
}

// ---------------------------------------------------------------------------
// O-projection GEMM, 8-WAVE (r19's proven lever applied): 512 threads on the
// 128x128 tile, wave = 64x32 output (acc[4][2]), one gl2lds per thread per
// matrix per tile, LDS 32 KB -> 2 blocks/CU x 8 waves = 16 waves/CU.
// ---------------------------------------------------------------------------
__global__ __launch_bounds__(512) void gemm_out(
        const unsigned short* __restrict__ Ab, const unsigned short* __restrict__ BT,
        const float* __restrict__ bias, float* __restrict__ C,
        int M, int N, int K) {
    __shared__ alignas(16) unsigned short Asmb[2][128][32];
    __shared__ alignas(16) unsigned short Bsm[2][128][32];
    const int m0 = blockIdx.x * 128, n0 = blockIdx.y * 128;
    const int lane = threadIdx.x & 63, wid = threadIdx.x >> 6;   // 0..7
    const int wr = wid >> 2, wc = wid & 3;
    const int cl = lane & 15, kg = lane >> 4;

    f32x4 acc[4][2] = {};

    auto STAGE = [&](int buf, int k0) {
        int base = wid * 16;
        int row = base + (lane >> 2);
        int cs = (lane & 3) ^ ((row >> 1) & 3);
        GL2LDS(Ab + (size_t)(m0 + row) * K + k0 + cs * 8, &Asmb[buf][base][0]);
        GL2LDS(BT + (size_t)(n0 + row) * K + k0 + cs * 8, &Bsm[buf][base][0]);
    };

    STAGE(0, 0);
    __syncthreads();

    for (int k0 = 0; k0 < K; k0 += 32) {
        int cur = (k0 >> 5) & 1;
        if (k0 + 32 < K) STAGE(cur ^ 1, k0 + 32);

        bf16x8 af[4], bfv[2];
#pragma unroll
        for (int mi = 0; mi < 4; ++mi) {
            int r = wr * 64 + mi * 16 + cl;
            af[mi] = *(const bf16x8*)&Asmb[cur][r][(kg ^ ((r >> 1) & 3)) * 8];
        }
#pragma unroll
        for (int ni = 0; ni < 2; ++ni) {
            int r = wc * 32 + ni * 16 + cl;
            bfv[ni] = *(const bf16x8*)&Bsm[cur][r][(kg ^ ((r >> 1) & 3)) * 8];
        }
#pragma unroll
        for (int mi = 0; mi < 4; ++mi)
#pragma unroll
            for (int ni = 0; ni < 2; ++ni)
                acc[mi][ni] = __builtin_amdgcn_mfma_f32_16x16x32_bf16(
                    af[mi], bfv[ni], acc[mi][ni], 0, 0, 0);
        __syncthreads();
    }

    const int rl = (lane >> 4) * 4;
#pragma unroll
    for (int mi = 0; mi < 4; ++mi) {
#pragma unroll
        for (int ni = 0; ni < 2; ++ni) {
            int row = m0 + wr * 64 + mi * 16 + rl;
            int col = n0 + wc * 32 + ni * 16 + cl;
            float bv = bias[col];
            f32x4 v = acc[mi][ni];
#pragma unroll
            for (int j = 0; j < 4; ++j)
                C[(size_t)(row + j) * N + col] = v[j] + bv;
        }
    }
}

// ---------------------------------------------------------------------------
// Flash attention v6.1 (byte-identical to rounds 21-23): 8 waves x 32 q-rows,
// KBLK=128, swapped QK^T, mask-seeded fixed-max softmax, interleaved
// QK->PV, ones-MFMA row sums, shuffle-free epilogue.
// ---------------------------------------------------------------------------
__global__ __launch_bounds__(512, 4) void attn_kernel(
        const unsigned short* __restrict__ Qp, const unsigned short* __restrict__ Kp,
        const unsigned short* __restrict__ VT, const float* __restrict__ MA,
        unsigned short* __restrict__ O) {
    __shared__ alignas(16) unsigned short Klds[2][128][64];
    __shared__ alignas(16) unsigned short Vlds[2][64][128];
    const int lane = threadIdx.x & 63, wid = threadIdx.x >> 6;   // wid 0..7
    const int bh = blockIdx.x;
    const int b = bh >> 4, h = bh & 15;
    const int qt = blockIdx.y;
    const int qrow0 = qt * 256 + wid * 32;
    const int cl = lane & 15, kg = lane >> 4;

    bf16x8 qf[2][2];
#pragma unroll
    for (int qh = 0; qh < 2; ++qh)
#pragma unroll
        for (int kh = 0; kh < 2; ++kh)
            qf[qh][kh] = *(const bf16x8*)&Qp[(size_t)(b * SS + qrow0 + qh * 16 + cl) * SD
                                            + h * 64 + kh * 32 + kg * 8];

    const float* MAb = MA + b * SS;

    bf16x8 onesf;
#pragma unroll
    for (int e = 0; e < 8; ++e) onesf[e] = (__bf16)1.0f;

    f32x4 oacc[2][4] = {};
    f32x4 lacc[2] = {};

    auto STAGE = [&](int buf, int tt) {
        int kt = (tt & 15) * 128;
        {
            int r8 = lane >> 3, c8 = lane & 7;
#pragma unroll
            for (int i = 0; i < 2; ++i) {
                int r = i * 64 + wid * 8 + r8;
                int cs = c8 ^ (r & 7);
                GL2LDS(Kp + (size_t)(b * SS + kt + r) * SD + h * 64 + cs * 8,
                       &Klds[buf][i * 64 + wid * 8][0]);
            }
        }
        {
            int r16 = lane >> 4, c16 = lane & 15;
#pragma unroll
            for (int i = 0; i < 2; ++i) {
                int r = i * 32 + wid * 4 + r16;
                int cs = (c16 & 8) | ((c16 & 7) ^ (r & 7));
                GL2LDS(VT + (size_t)(b * 1024 + h * 64 + r) * 2048 + kt + cs * 8,
                       &Vlds[buf][i * 32 + wid * 4][0]);
            }
        }
    };

    auto QKCOL = [&](int buf, int kt, int cf, f32x4* sv) {
        int r = cf * 16 + cl;
        bf16x8 kf0 = *(const bf16x8*)&Klds[buf][r][((0 + kg) ^ (r & 7)) * 8];
        bf16x8 kf1 = *(const bf16x8*)&Klds[buf][r][((4 + kg) ^ (r & 7)) * 8];
        f32x4 M = *(const f32x4*)&MAb[kt + cf * 16 + 4 * kg];
        __builtin_amdgcn_s_setprio(1);
#pragma unroll
        for (int qh = 0; qh < 2; ++qh) {
            f32x4 s = M;
            s = __builtin_amdgcn_mfma_f32_16x16x32_bf16(kf0, qf[qh][0], s, 0, 0, 0);
            s = __builtin_amdgcn_mfma_f32_16x16x32_bf16(kf1, qf[qh][1], s, 0, 0, 0);
#pragma unroll
            for (int j = 0; j < 4; ++j)
                s[j] = __builtin_amdgcn_exp2f(s[j]);
            sv[qh] = s;
        }
        __builtin_amdgcn_s_setprio(0);
    };

    auto STEP = [&](int buf, int t) {
        int kt = t * 128;
#pragma unroll
        for (int ks = 0; ks < 4; ++ks) {
            f32x4 sA[2], sB[2];
            QKCOL(buf, kt, ks, sA);
            QKCOL(buf, kt, ks + 4, sB);
            bf16x8 pa[2];
#pragma unroll
            for (int qh = 0; qh < 2; ++qh) {
                pa[qh][0] = (__bf16)sA[qh][0];
                pa[qh][1] = (__bf16)sA[qh][1];
                pa[qh][2] = (__bf16)sA[qh][2];
                pa[qh][3] = (__bf16)sA[qh][3];
                pa[qh][4] = (__bf16)sB[qh][0];
                pa[qh][5] = (__bf16)sB[qh][1];
                pa[qh][6] = (__bf16)sB[qh][2];
                pa[qh][7] = (__bf16)sB[qh][3];
            }
            __builtin_amdgcn_s_setprio(1);
#pragma unroll
            for (int qh = 0; qh < 2; ++qh)
                lacc[qh] = __builtin_amdgcn_mfma_f32_16x16x32_bf16(
                    pa[qh], onesf, lacc[qh], 0, 0, 0);
#pragma unroll
            for (int nf = 0; nf < 4; ++nf) {
                int d = nf * 16 + cl;
                int c16a = 2 * ks + (kg >> 1);
                int c16b = 2 * (ks + 4) + (kg >> 1);
                int cha = (c16a & 8) | ((c16a & 7) ^ (d & 7));
                int chb = (c16b & 8) | ((c16b & 7) ^ (d & 7));
                const char* vb = (const char*)&Vlds[buf][d][0];
                uint2v lo = *(const uint2v*)(vb + cha * 16 + (kg & 1) * 8);
                uint2v hi = *(const uint2v*)(vb + chb * 16 + (kg & 1) * 8);
                bf16x8 vf;
                *(uint2v*)&vf = lo;
                *((uint2v*)&vf + 1) = hi;
#pragma unroll
                for (int qh = 0; qh < 2; ++qh)
                    oacc[qh][nf] = __builtin_amdgcn_mfma_f32_16x16x32_bf16(
                        pa[qh], vf, oacc[qh][nf], 0, 0, 0);
            }
            __builtin_amdgcn_s_setprio(0);
        }
    };

    STAGE(0, 0);
    __syncthreads();
    for (int t = 0; t < 16; ++t) {
        int cur = t & 1;
        STAGE(cur ^ 1, t + 1);
        STEP(cur, t);
        __syncthreads();
    }

#pragma unroll
    for (int qh = 0; qh < 2; ++qh) {
#pragma unroll
        for (int j = 0; j < 4; ++j) {
            float inv = 1.0f / lacc[qh][j];
#pragma unroll
            for (int nf = 0; nf < 4; ++nf)
                O[(size_t)(b * SS + qrow0 + qh * 16 + 4 * kg + j) * SD + h * 64 + nf * 16 + cl] =
                    f2bf_(oacc[qh][nf][j] * inv);
        }
    }
}

// ---------------------------------------------------------------------------
extern "C" void kernel_launch(void* const* d_in, const int* in_sizes, int n_in,
                              void* d_out, int out_size, void* d_ws, size_t ws_size,
                              hipStream_t stream) {
    const float* q  = (const float*)d_in[0];
    const float* k  = (const float*)d_in[1];
    const float* v  = (const float*)d_in[2];
    const int*   mk = (const int*)d_in[3];
    const float* wq = (const float*)d_in[4];
    const float* bq = (const float*)d_in[5];
    const float* wk = (const float*)d_in[6];
    const float* bk = (const float*)d_in[7];
    const float* wv = (const float*)d_in[8];
    const float* bv = (const float*)d_in[9];
    const float* wo = (const float*)d_in[10];
    const float* bo = (const float*)d_in[11];
    float* out = (float*)d_out;

    char* ws = (char*)d_ws;
    unsigned short* WT  = (unsigned short*)ws;                   // 8 MB
    unsigned short* X   = (unsigned short*)(ws + 8388608);       // attn out (bf16)
    unsigned short* Qh  = (unsigned short*)(ws + 25165824);
    unsigned short* Kh  = (unsigned short*)(ws + 41943040);
    unsigned short* VTr = (unsigned short*)(ws + 58720256);
    float*          MAf = (float*)(ws + 75497472);               // 32 KB

    const float QSCL = 0.125f * 1.4426950408889634f;  // 1/sqrt(64) * log2(e)

    transpose4<<<dim3(32, 32, 5), dim3(32, 8), 0, stream>>>(
        wq, wk, wv, wo, WT, mk, MAf);

    gemm_qkv<<<dim3(64, 8, 3), dim3(512), 0, stream>>>(
        q, k, v, WT, bq, bk, bv, Qh, Kh, VTr, QSCL);

    attn_kernel<<<dim3(64, 8), dim3(512), 0, stream>>>(Qh, Kh, VTr, MAf, X);

    gemm_out<<<dim3(64, 8), dim3(512), 0, stream>>>(
        X, WT + 3 * 1048576, bo, out, 8192, 1024, 1024);
}